// Round 13
// baseline (1852.329 us; speedup 1.0000x reference)
//
#include <hip/hip_runtime.h>
#include <math.h>

// Problem constants
// H=256, D_IN=22, T=384, 4H=1024, N_R=N_L=384, H1=1024, H2=512, H3=1024, RRI=2

typedef _Float16 half2_t __attribute__((ext_vector_type(2)));

__device__ __forceinline__ float fast_sig(float x) {
    float e = __expf(-x);
    return __builtin_amdgcn_rcpf(1.f + e);
}
__device__ __forceinline__ float fast_tanh(float x) {
    x = fminf(fmaxf(x, -30.f), 30.f);
    float e = __expf(2.f * x);
    return (e - 1.f) * __builtin_amdgcn_rcpf(e + 1.f);
}

// ---------------------------------------------------------------------------
// prep: b0sum = bih0+bhh0, b1sum = bih1+bhh1, W3sum[n][k] = W3[n][k]+W3[n][512+k],
//       woutT[2c+k] = Wout[k][c]
// ---------------------------------------------------------------------------
__global__ __launch_bounds__(256) void prep_kernel(
    const float* __restrict__ bih0, const float* __restrict__ bhh0,
    const float* __restrict__ bih1, const float* __restrict__ bhh1,
    const float* __restrict__ W3,   const float* __restrict__ Wout,
    float* __restrict__ b0sum, float* __restrict__ b1sum,
    float* __restrict__ W3sum, float* __restrict__ woutT)
{
    int idx = blockIdx.x * 256 + threadIdx.x;
    int stride = gridDim.x * 256;
    if (idx < 2048) {
        b0sum[idx] = bih0[idx] + bhh0[idx];
        b1sum[idx] = bih1[idx] + bhh1[idx];
        woutT[idx] = Wout[(idx & 1) * 1024 + (idx >> 1)];
    }
    for (int i = idx; i < 1024 * 512; i += stride) {
        int n = i >> 9, k = i & 511;
        W3sum[i] = W3[n * 1024 + k] + W3[n * 1024 + 512 + k];
    }
}

// ---------------------------------------------------------------------------
// proj0: pre0[(seq*2+dir)][t][o] = x[t] @ Wih0[dir].T + b0sum[dir]
// ---------------------------------------------------------------------------
__global__ __launch_bounds__(256) void proj0_kernel(
    const float* __restrict__ v_r, const float* __restrict__ v_l,
    const float* __restrict__ Wih0, const float* __restrict__ b0sum,
    float* __restrict__ pre0)
{
    int t = blockIdx.x;
    int sd = blockIdx.y;            // seq*2 + dir
    int seq = sd >> 1, dir = sd & 1;
    const float* x = (seq ? v_l : v_r) + t * 22;
    __shared__ float sx[22];
    if (threadIdx.x < 22) sx[threadIdx.x] = x[threadIdx.x];
    __syncthreads();
#pragma unroll
    for (int q = 0; q < 4; ++q) {
        int o = q * 256 + threadIdx.x;
        const float* wr = Wih0 + (size_t)(dir * 1024 + o) * 22;
        float acc = b0sum[dir * 1024 + o];
#pragma unroll
        for (int d = 0; d < 22; ++d) acc += sx[d] * wr[d];
        pre0[((size_t)sd * 384 + t) * 1024 + o] = acc;
    }
}

// ---------------------------------------------------------------------------
// LSTM recurrence, v13: single WG per chain, 1024 threads, ONE gate row per
// thread — register demand fits the 128-VGPR tier BY DESIGN.
// R11/R12 lesson: the allocator will not exceed 128 VGPRs/thread no matter
// what (__launch_bounds__ min-waves, amdgpu_waves_per_eu both failed); asm
// pins stop remat, not spill. So: per-thread weights = 128 half2 (one row,
// full K=256) split 92 regs + 36 LDS -> ~117 total VGPR demand < 128.
// 4 blocks x 1024 threads (16 waves/CU, 4 waves/SIMD).
// Thread o=tid owns gate row o: preact computed entirely in-thread (no
// reduction). Gate combine via LDS gbuf[1024] fp32: write own preact,
// barrier A, read 4 gates for j=tid&255 (b32 contiguous, conflict-free),
// all threads compute c/h redundantly (bit-identical — same LDS inputs, R8);
// tid<256 writes hh[pn] f16, tid in [256,512) writes out. Barrier B.
// hh[2][128] half2 parity dbuf; h broadcast reads (same addr all lanes).
// LDS: wl[9][1024] float4 (147 KB weights, lane stride 16B = canonical
// conflict-free) + hh 1 KB + gbuf 4 KB = 149 KB <= 160.
// Compute floor: 131K fdot2 / 128 per cyc = 1024 cyc/step; LDS weight
// stream 147 KB / 256 B/cyc = 575 cyc (overlaps); + ~300 gates/barriers.
// ---------------------------------------------------------------------------
__global__ __launch_bounds__(1024, 4) void lstm_rec_kernel(
    const float* __restrict__ Whh,   // [2][1024][256] fp32
    const float* __restrict__ pre,   // layer0: [(seq*2+dir)][384][1024]; layer1: [(seq*384+t)][2][1024]
    float* __restrict__ out,         // [2][384][512]  (cols: dir*256 + j)
    int layer)
{
    const int chain = blockIdx.x;            // 0..3
    const int seq = chain >> 1, dir = chain & 1;
    const int tid = threadIdx.x;             // = gate row o
    const int jj = tid & 255;                // h index this thread updates

    __shared__ __align__(16) float4 wl[9][1024];     // 147 KB: k-pairs 92..127
    __shared__ __align__(16) half2_t hh[2][128];     // h (f16 pairs), parity dbuf
    __shared__ float gbuf[1024];                     // gate preacts

    // ---- Weights: row tid, k-pairs 0..91 in regs, 92..127 in LDS ----
    float wA[92];
    {
        const float* wr = Whh + (((size_t)(dir * 1024 + tid)) << 8);
#pragma unroll
        for (int q = 0; q < 92; ++q) {
            float2 v = *(const float2*)(wr + 2 * q);
            half2_t h2; h2.x = (_Float16)v.x; h2.y = (_Float16)v.y;
            wA[q] = __builtin_bit_cast(float, h2);
        }
        for (int c = 0; c < 9; ++c) {
            float4 pk;
            float* pf = (float*)&pk;
#pragma unroll
            for (int i = 0; i < 4; ++i) {
                float2 v = *(const float2*)(wr + 184 + 8 * c + 2 * i);
                half2_t h2; h2.x = (_Float16)v.x; h2.y = (_Float16)v.y;
                pf[i] = __builtin_bit_cast(float, h2);
            }
            wl[c][tid] = pk;
        }
    }
#pragma unroll
    for (int q = 0; q < 92; ++q) asm volatile("" : "+v"(wA[q]));

    if (tid < 128) hh[0][tid] = half2_t{(_Float16)0.f, (_Float16)0.f};
    float cstate = 0.f;                      // redundant (4 threads per j), bit-identical
    __syncthreads();

    for (int s = 0; s < 384; ++s) {
        const int t = dir ? (383 - s) : s;
        const float* pre_t = (layer == 0)
            ? pre + ((size_t)(seq * 2 + dir) * 384 + t) * 1024
            : pre + (((size_t)(seq * 384 + t)) * 2 + dir) * 1024;
        float pv = pre_t[tid];               // issued early, drains under fdot

        const int par = s & 1;
        const float4* hb = (const float4*)hh[par];   // 32 chunks, broadcast
        float acc = 0.f;

        // k-pairs 0..91 from registers (chunks 0..22)
#pragma unroll
        for (int m = 0; m < 23; ++m) {
            float4 hv4 = hb[m];
            const float he[4] = {hv4.x, hv4.y, hv4.z, hv4.w};
#pragma unroll
            for (int e = 0; e < 4; ++e) {
                half2_t hv = __builtin_bit_cast(half2_t, he[e]);
                acc = __builtin_amdgcn_fdot2(
                    __builtin_bit_cast(half2_t, wA[4 * m + e]), hv, acc, false);
            }
        }
        // k-pairs 92..127 from LDS (chunks 23..31)
#pragma unroll
        for (int m = 23; m < 32; ++m) {
            float4 hv4 = hb[m];
            float4 wv4 = wl[m - 23][tid];
            const float he[4] = {hv4.x, hv4.y, hv4.z, hv4.w};
            const float we[4] = {wv4.x, wv4.y, wv4.z, wv4.w};
#pragma unroll
            for (int e = 0; e < 4; ++e) {
                half2_t hv = __builtin_bit_cast(half2_t, he[e]);
                acc = __builtin_amdgcn_fdot2(
                    __builtin_bit_cast(half2_t, we[e]), hv, acc, false);
            }
        }

        gbuf[tid] = acc + pv;                // full preact for row tid
        __syncthreads();                     // barrier A: gbuf ready

        // Every thread: gates for j = tid&255, redundant bit-identical update.
        float gi = gbuf[jj];
        float gf = gbuf[256 + jj];
        float gg = gbuf[512 + jj];
        float go = gbuf[768 + jj];
        float iv = fast_sig(gi);
        float fv = fast_sig(gf);
        float gv = fast_tanh(gg);
        float ov = fast_sig(go);
        cstate = fv * cstate + iv * gv;
        float h = ov * fast_tanh(cstate);

        if (tid < 256) {
            ((unsigned short*)hh[par ^ 1])[tid] =
                __builtin_bit_cast(unsigned short, (_Float16)h);
        } else if (tid < 512) {
            out[((size_t)seq * 384 + t) * 512 + dir * 256 + jj] = h;
        }
        __syncthreads();                     // barrier B: hh[pn] ready
    }
}

// ---------------------------------------------------------------------------
// Generic NT GEMM: C[M][N] = act(scale * A[M][K] @ W[N][K]^T + bias[N])
// ---------------------------------------------------------------------------
__global__ __launch_bounds__(256) void gemm_nt_kernel(
    const float* __restrict__ A, const float* __restrict__ W,
    const float* __restrict__ bias, float* __restrict__ C,
    int M, int N, int K, float scale, int do_relu)
{
    __shared__ float As[32][68];
    __shared__ float Ws[32][68];
    const int tid = threadIdx.x;
    const int n0 = blockIdx.x * 64, m0 = blockIdx.y * 64;
    const int lr = tid >> 2;
    const int lk = (tid & 3) * 8;
    const int tm = tid >> 4, tn = tid & 15;
    float acc[4][4];
#pragma unroll
    for (int i = 0; i < 4; ++i)
#pragma unroll
        for (int j = 0; j < 4; ++j) acc[i][j] = 0.f;

    for (int kc = 0; kc < K; kc += 32) {
        float4 a0 = *(const float4*)(A + (size_t)(m0 + lr) * K + kc + lk);
        float4 a1 = *(const float4*)(A + (size_t)(m0 + lr) * K + kc + lk + 4);
        float4 w0 = *(const float4*)(W + (size_t)(n0 + lr) * K + kc + lk);
        float4 w1 = *(const float4*)(W + (size_t)(n0 + lr) * K + kc + lk + 4);
        __syncthreads();
        As[lk + 0][lr] = a0.x; As[lk + 1][lr] = a0.y; As[lk + 2][lr] = a0.z; As[lk + 3][lr] = a0.w;
        As[lk + 4][lr] = a1.x; As[lk + 5][lr] = a1.y; As[lk + 6][lr] = a1.z; As[lk + 7][lr] = a1.w;
        Ws[lk + 0][lr] = w0.x; Ws[lk + 1][lr] = w0.y; Ws[lk + 2][lr] = w0.z; Ws[lk + 3][lr] = w0.w;
        Ws[lk + 4][lr] = w1.x; Ws[lk + 5][lr] = w1.y; Ws[lk + 6][lr] = w1.z; Ws[lk + 7][lr] = w1.w;
        __syncthreads();
#pragma unroll
        for (int kk = 0; kk < 32; ++kk) {
            float4 av = *(const float4*)&As[kk][tm * 4];
            float4 wv = *(const float4*)&Ws[kk][tn * 4];
            acc[0][0] += av.x * wv.x; acc[0][1] += av.x * wv.y; acc[0][2] += av.x * wv.z; acc[0][3] += av.x * wv.w;
            acc[1][0] += av.y * wv.x; acc[1][1] += av.y * wv.y; acc[1][2] += av.y * wv.z; acc[1][3] += av.y * wv.w;
            acc[2][0] += av.z * wv.x; acc[2][1] += av.z * wv.y; acc[2][2] += av.z * wv.z; acc[2][3] += av.z * wv.w;
            acc[3][0] += av.w * wv.x; acc[3][1] += av.w * wv.y; acc[3][2] += av.w * wv.z; acc[3][3] += av.w * wv.w;
        }
    }
    float4 bv = make_float4(0.f, 0.f, 0.f, 0.f);
    if (bias) bv = *(const float4*)(bias + n0 + tn * 4);
#pragma unroll
    for (int i = 0; i < 4; ++i) {
        int m = m0 + tm * 4 + i;
        float4 v;
        v.x = scale * acc[i][0] + bv.x;
        v.y = scale * acc[i][1] + bv.y;
        v.z = scale * acc[i][2] + bv.z;
        v.w = scale * acc[i][3] + bv.w;
        if (do_relu) {
            v.x = fmaxf(v.x, 0.f); v.y = fmaxf(v.y, 0.f);
            v.z = fmaxf(v.z, 0.f); v.w = fmaxf(v.w, 0.f);
        }
        *(float4*)(C + (size_t)m * N + n0 + tn * 4) = v;
    }
}

// ---------------------------------------------------------------------------
// pairwise: out[i][j][:] = log_softmax( sum_c relu(ur'[i][c]+ul[j][c]) * woutT[c][:] + bout )
// Stride 132 + row remap (il=ii/ii+16, jl=jj/jj+16) -> <=2-way conflicts (R7 fix).
// ---------------------------------------------------------------------------
__global__ __launch_bounds__(256) void pairwise_kernel(
    const float* __restrict__ u,      // [768][1024]
    const float* __restrict__ woutT,  // [1024][2]
    const float* __restrict__ bout,   // [2]
    float* __restrict__ out)          // [384][384][2]
{
    __shared__ float Ur[32][132];
    __shared__ float Ul[32][132];
    __shared__ float Wo[256];
    const int tid = threadIdx.x;
    const int j0 = blockIdx.x * 32, i0 = blockIdx.y * 32;
    const int ii = tid >> 4, jj = tid & 15;
    const int il0 = ii, il1 = ii + 16;
    const int jl0 = jj, jl1 = jj + 16;
    float acc000 = 0.f, acc001 = 0.f, acc010 = 0.f, acc011 = 0.f;
    float acc100 = 0.f, acc101 = 0.f, acc110 = 0.f, acc111 = 0.f;
    const int lrw = tid >> 3;
    const int lcb = (tid & 7) * 16;

    for (int cc = 0; cc < 1024; cc += 128) {
        __syncthreads();
#pragma unroll
        for (int q = 0; q < 4; ++q) {
            *(float4*)&Ur[lrw][lcb + 4 * q] =
                *(const float4*)(u + (size_t)(i0 + lrw) * 1024 + cc + lcb + 4 * q);
            *(float4*)&Ul[lrw][lcb + 4 * q] =
                *(const float4*)(u + (size_t)(384 + j0 + lrw) * 1024 + cc + lcb + 4 * q);
        }
        if (tid < 128)
            *(float2*)&Wo[tid * 2] = *(const float2*)(woutT + (size_t)(cc + tid) * 2);
        __syncthreads();

        for (int c = 0; c < 128; c += 4) {
            float4 a0  = *(const float4*)&Ur[il0][c];
            float4 a1  = *(const float4*)&Ur[il1][c];
            float4 b0v = *(const float4*)&Ul[jl0][c];
            float4 b1v = *(const float4*)&Ul[jl1][c];
            float4 wA4 = *(const float4*)&Wo[c * 2];
            float4 wB4 = *(const float4*)&Wo[c * 2 + 4];
#define PW_STEP(AX, W0, W1)                                   \
            { float rr;                                       \
              rr = fmaxf(a0.AX + b0v.AX, 0.f); acc000 += rr*(W0); acc001 += rr*(W1); \
              rr = fmaxf(a0.AX + b1v.AX, 0.f); acc010 += rr*(W0); acc011 += rr*(W1); \
              rr = fmaxf(a1.AX + b0v.AX, 0.f); acc100 += rr*(W0); acc101 += rr*(W1); \
              rr = fmaxf(a1.AX + b1v.AX, 0.f); acc110 += rr*(W0); acc111 += rr*(W1); }
            PW_STEP(x, wA4.x, wA4.y)
            PW_STEP(y, wA4.z, wA4.w)
            PW_STEP(z, wB4.x, wB4.y)
            PW_STEP(w, wB4.z, wB4.w)
#undef PW_STEP
        }
    }
    float2 bo = *(const float2*)bout;
    float pa[2][2][2] = {{{acc000, acc001}, {acc010, acc011}},
                         {{acc100, acc101}, {acc110, acc111}}};
#pragma unroll
    for (int pi = 0; pi < 2; ++pi)
#pragma unroll
        for (int pj = 0; pj < 2; ++pj) {
            float l0 = pa[pi][pj][0] + bo.x;
            float l1 = pa[pi][pj][1] + bo.y;
            float m = fmaxf(l0, l1);
            float lse = m + logf(expf(l0 - m) + expf(l1 - m));
            int ig = i0 + ii + 16 * pi;
            int jg = j0 + jj + 16 * pj;
            float2 o2; o2.x = l0 - lse; o2.y = l1 - lse;
            *(float2*)(out + ((size_t)ig * 384 + jg) * 2) = o2;
        }
}

// ---------------------------------------------------------------------------
extern "C" void kernel_launch(void* const* d_in, const int* in_sizes, int n_in,
                              void* d_out, int out_size, void* d_ws, size_t ws_size,
                              hipStream_t stream)
{
    const float* v_r  = (const float*)d_in[0];
    const float* v_l  = (const float*)d_in[1];
    const float* Wih0 = (const float*)d_in[2];
    const float* Whh0 = (const float*)d_in[3];
    const float* bih0 = (const float*)d_in[4];
    const float* bhh0 = (const float*)d_in[5];
    const float* Wih1 = (const float*)d_in[6];
    const float* Whh1 = (const float*)d_in[7];
    const float* bih1 = (const float*)d_in[8];
    const float* bhh1 = (const float*)d_in[9];
    const float* W1   = (const float*)d_in[10];
    const float* b1   = (const float*)d_in[11];
    const float* W2   = (const float*)d_in[12];
    const float* b2   = (const float*)d_in[13];
    const float* W3   = (const float*)d_in[14];
    const float* b3   = (const float*)d_in[15];
    const float* Wout = (const float*)d_in[16];
    const float* bout = (const float*)d_in[17];
    float* out = (float*)d_out;

    float* ws = (float*)d_ws;
    size_t off = 0;
    float* b0sum = ws + off; off += 2048;
    float* b1sum = ws + off; off += 2048;
    float* W3sum = ws + off; off += 1024 * 512;
    float* woutT = ws + off; off += 2048;
    float* pre0  = ws + off; off += (size_t)4 * 384 * 1024;
    float* out0  = ws + off; off += (size_t)2 * 384 * 512;
    float* pre1  = ws + off; off += (size_t)768 * 2048;
    float* out1  = ws + off; off += (size_t)2 * 384 * 512;
    float* h1    = ws + off; off += (size_t)768 * 1024;
    float* h2    = ws + off; off += (size_t)768 * 512;
    float* u     = ws + off; off += (size_t)768 * 1024;

    prep_kernel<<<512, 256, 0, stream>>>(bih0, bhh0, bih1, bhh1, W3, Wout,
                                         b0sum, b1sum, W3sum, woutT);
    proj0_kernel<<<dim3(384, 4), 256, 0, stream>>>(v_r, v_l, Wih0, b0sum, pre0);
    lstm_rec_kernel<<<4, 1024, 0, stream>>>(Whh0, pre0, out0, 0);
    gemm_nt_kernel<<<dim3(2048 / 64, 768 / 64), 256, 0, stream>>>(
        out0, Wih1, b1sum, pre1, 768, 2048, 512, 1.f, 0);
    lstm_rec_kernel<<<4, 1024, 0, stream>>>(Whh1, pre1, out1, 1);
    gemm_nt_kernel<<<dim3(1024 / 64, 768 / 64), 256, 0, stream>>>(
        out1, W1, b1, h1, 768, 1024, 512, 1.f, 1);
    gemm_nt_kernel<<<dim3(512 / 64, 768 / 64), 256, 0, stream>>>(
        h1, W2, b2, h2, 768, 512, 1024, 1.f, 1);
    gemm_nt_kernel<<<dim3(1024 / 64, 384 / 64), 256, 0, stream>>>(
        h2, W3sum, b3, u, 384, 1024, 512, 0.5f, 0);
    gemm_nt_kernel<<<dim3(1024 / 64, 384 / 64), 256, 0, stream>>>(
        h2 + (size_t)384 * 512, W3sum, nullptr, u + (size_t)384 * 1024, 384, 1024, 512, 0.5f, 0);
    pairwise_kernel<<<dim3(12, 12), 256, 0, stream>>>(u, woutT, bout, out);
}

// Round 14
// 1509.662 us; speedup vs baseline: 1.2270x; 1.2270x over previous
//
#include <hip/hip_runtime.h>
#include <math.h>

// Problem constants
// H=256, D_IN=22, T=384, 4H=1024, N_R=N_L=384, H1=1024, H2=512, H3=1024, RRI=2

typedef _Float16 half2_t __attribute__((ext_vector_type(2)));

__device__ __forceinline__ float fast_sig(float x) {
    float e = __expf(-x);
    return __builtin_amdgcn_rcpf(1.f + e);
}
__device__ __forceinline__ float fast_tanh(float x) {
    x = fminf(fmaxf(x, -30.f), 30.f);
    float e = __expf(2.f * x);
    return (e - 1.f) * __builtin_amdgcn_rcpf(e + 1.f);
}

// ---------------------------------------------------------------------------
// prep
// ---------------------------------------------------------------------------
__global__ __launch_bounds__(256) void prep_kernel(
    const float* __restrict__ bih0, const float* __restrict__ bhh0,
    const float* __restrict__ bih1, const float* __restrict__ bhh1,
    const float* __restrict__ W3,   const float* __restrict__ Wout,
    float* __restrict__ b0sum, float* __restrict__ b1sum,
    float* __restrict__ W3sum, float* __restrict__ woutT)
{
    int idx = blockIdx.x * 256 + threadIdx.x;
    int stride = gridDim.x * 256;
    if (idx < 2048) {
        b0sum[idx] = bih0[idx] + bhh0[idx];
        b1sum[idx] = bih1[idx] + bhh1[idx];
        woutT[idx] = Wout[(idx & 1) * 1024 + (idx >> 1)];
    }
    for (int i = idx; i < 1024 * 512; i += stride) {
        int n = i >> 9, k = i & 511;
        W3sum[i] = W3[n * 1024 + k] + W3[n * 1024 + 512 + k];
    }
}

// ---------------------------------------------------------------------------
// proj0
// ---------------------------------------------------------------------------
__global__ __launch_bounds__(256) void proj0_kernel(
    const float* __restrict__ v_r, const float* __restrict__ v_l,
    const float* __restrict__ Wih0, const float* __restrict__ b0sum,
    float* __restrict__ pre0)
{
    int t = blockIdx.x;
    int sd = blockIdx.y;            // seq*2 + dir
    int seq = sd >> 1, dir = sd & 1;
    const float* x = (seq ? v_l : v_r) + t * 22;
    __shared__ float sx[22];
    if (threadIdx.x < 22) sx[threadIdx.x] = x[threadIdx.x];
    __syncthreads();
#pragma unroll
    for (int q = 0; q < 4; ++q) {
        int o = q * 256 + threadIdx.x;
        const float* wr = Wih0 + (size_t)(dir * 1024 + o) * 22;
        float acc = b0sum[dir * 1024 + o];
#pragma unroll
        for (int d = 0; d < 22; ++d) acc += sx[d] * wr[d];
        pre0[((size_t)sd * 384 + t) * 1024 + o] = acc;
    }
}

// ---------------------------------------------------------------------------
// LSTM recurrence, v14 = R10's v9 protocol + weights SIZED TO THE REAL
// REGISTER BUDGET.
// R11/R12/R13 lesson: the allocator caps 512-thr blocks at ~104-128 VGPRs
// and SPILLS any pinned array beyond that (asm pins stop remat, not spill;
// launch_bounds min-waves and amdgpu_waves_per_eu are ignored). R10's 128
// pinned floats @ VGPR=104 were partially spilled -> its ~3475 cyc/step
// included hidden scratch reload. v14: 64 pinned floats (fits), remaining
// weights in LDS.
// Topology (R10-proven): grid 16, chain=b&7 (>=4 exit), w=b>>3 in {0,1};
// chain's 2 WGs on XCD chain. Thread t: jloc=t>>2, ks=t&3; owns ALL 4 gate
// rows for jj=(w<<7)+jloc over k-quarter:
//   own-half quarter  k in [128w +32ks, +32):  4g x 16 half2 = 64 regs (pin)
//   peer-half quarter k in [128wp+32ks, +32):  4g x 4 float4 -> wl[16][512]
//     (128 KB LDS, 16B/lane stride = canonical conflict-free)
// Per step: [phase A: own-half fdot] [tid%8==7: poll peer h_{s-1}, tag s]
//           [barrier] [phase B: peer-half fdot (weights from LDS)]
//           [fold pre (lane ks owns gate ks); butterfly over 4 lanes -> ALL
//            lanes hold 4 gate sums; redundant bit-identical c/h (R8)]
//           [ks==0: hh[pn] f16 write | ks==1: out store |
//            tid%8==2: publish pair (tag s+1, shfl_xor(4) partner) ]
//           [barrier]
// Publish precedes poll in program order per wave across steps; tags
// strictly increase -> deadlock-free (R4/R8). pub[4][2][128], strides
// verified (R9 bug). Bounded s_sleep spin.
// ---------------------------------------------------------------------------
__global__ __launch_bounds__(512) void lstm_rec_kernel(
    const float* __restrict__ Whh,   // [2][1024][256] fp32
    const float* __restrict__ pre,   // layer0: [(seq*2+dir)][384][1024]; layer1: [(seq*384+t)][2][1024]
    float* __restrict__ out,         // [2][384][512]  (cols: dir*256 + j)
    unsigned long long* pub,         // [4 chains][2 parity][128]
    int layer)
{
    const int b = blockIdx.x;
    const int chain = b & 7;                 // = XCD id under %8 round-robin
    const int w = b >> 3;                    // 0 or 1
    if (chain >= 4) return;
    const int seq = chain >> 1, dir = chain & 1;
    const int tid = threadIdx.x;
    const int ks = tid & 3;                  // k-quarter within each half
    const int jloc = tid >> 2;               // 0..127
    const int jj = (w << 7) + jloc;          // own h index
    const int wp = 1 - w;

    __shared__ __align__(16) float4 wl[16][512];    // 128 KB peer-half weights
    __shared__ __align__(16) half2_t hh[2][128];    // h pairs, parity dbuf

    // Own-half quarter weights -> 64 pinned regs. Layout wA[g*16 + 4m + e]
    // = half2 index (w<<6)+(ks<<4)+4m+e of row g*256+jj.
    float wA[64];
    {
#pragma unroll
        for (int g = 0; g < 4; ++g) {
            const float* wr = Whh + (((size_t)(dir * 1024 + g * 256 + jj)) << 8);
            const float* po = wr + (w << 7) + (ks << 5);
            const float* pr = wr + (wp << 7) + (ks << 5);
#pragma unroll
            for (int q = 0; q < 16; ++q) {
                float2 v = *(const float2*)(po + 2 * q);
                half2_t h2; h2.x = (_Float16)v.x; h2.y = (_Float16)v.y;
                wA[g * 16 + q] = __builtin_bit_cast(float, h2);
            }
            for (int cc = 0; cc < 4; ++cc) {
                float4 pk; float* pf = (float*)&pk;
#pragma unroll
                for (int e = 0; e < 4; ++e) {
                    float2 v = *(const float2*)(pr + 8 * cc + 2 * e);
                    half2_t h2; h2.x = (_Float16)v.x; h2.y = (_Float16)v.y;
                    pf[e] = __builtin_bit_cast(float, h2);
                }
                wl[g * 4 + cc][tid] = pk;
            }
        }
    }
#pragma unroll
    for (int q = 0; q < 64; ++q) asm volatile("" : "+v"(wA[q]));

    if (tid < 128) hh[0][tid] = half2_t{(_Float16)0.f, (_Float16)0.f};
    float cstate = 0.f;                      // redundant, bit-identical in 4 k-lanes

    const bool isPub  = (ks == 2) && ((jloc & 1) == 0);   // tid%8==2
    const bool isOut  = (ks == 1);
    const bool isPoll = (ks == 3) && ((jloc & 1) == 1);   // tid%8==7
    const int  p  = jloc >> 1;               // pair index 0..63
    __syncthreads();

    for (int s = 0; s < 384; ++s) {
        const int t = dir ? (383 - s) : s;
        const float* pre_t = (layer == 0)
            ? pre + ((size_t)(seq * 2 + dir) * 384 + t) * 1024
            : pre + (((size_t)(seq * 384 + t)) * 2 + dir) * 1024;
        float pv = pre_t[(ks << 8) + jj];    // gate-ks preact, drains under fdot

        const int par = s & 1;
        const float4* hb = (const float4*)hh[par];
        float a0 = 0.f, a1 = 0.f, a2 = 0.f, a3 = 0.f;

        // ---- Phase A: own-half quarter (h local, weights in regs) ----
#pragma unroll
        for (int m = 0; m < 4; ++m) {
            float4 hv4 = hb[(w << 4) + (ks << 2) + m];
            const float he[4] = {hv4.x, hv4.y, hv4.z, hv4.w};
#pragma unroll
            for (int e = 0; e < 4; ++e) {
                half2_t hv = __builtin_bit_cast(half2_t, he[e]);
                int q = 4 * m + e;
                a0 = __builtin_amdgcn_fdot2(__builtin_bit_cast(half2_t, wA[q]),      hv, a0, false);
                a1 = __builtin_amdgcn_fdot2(__builtin_bit_cast(half2_t, wA[16 + q]), hv, a1, false);
                a2 = __builtin_amdgcn_fdot2(__builtin_bit_cast(half2_t, wA[32 + q]), hv, a2, false);
                a3 = __builtin_amdgcn_fdot2(__builtin_bit_cast(half2_t, wA[48 + q]), hv, a3, false);
            }
        }
        // ---- Poll peer h_{s-1} (tag s) — overlapped with phase A ----
        if (isPoll && s > 0) {
            unsigned long long* pb = pub + ((size_t)chain * 2 + par) * 128;
            const unsigned long long* src = &pb[(wp << 6) + p];
            const unsigned expect = (unsigned)s;
            unsigned long long v =
                __hip_atomic_load(src, __ATOMIC_RELAXED, __HIP_MEMORY_SCOPE_AGENT);
            if ((unsigned)(v >> 32) != expect) {
                for (int it = 0; it < 65536; ++it) {
                    __builtin_amdgcn_s_sleep(1);
                    v = __hip_atomic_load(src, __ATOMIC_RELAXED, __HIP_MEMORY_SCOPE_AGENT);
                    if ((unsigned)(v >> 32) == expect) break;
                }
            }
            hh[par][(wp << 6) + p] = __builtin_bit_cast(half2_t, (unsigned)v);
        }
        __syncthreads();                     // peer h_{s-1} visible

        // ---- Phase B: peer-half quarter (weights from LDS) ----
#pragma unroll
        for (int m = 0; m < 4; ++m) {
            float4 hv4 = hb[(wp << 4) + (ks << 2) + m];
            float4 w0 = wl[m][tid];
            float4 w1 = wl[4 + m][tid];
            float4 w2 = wl[8 + m][tid];
            float4 w3 = wl[12 + m][tid];
            const float he[4] = {hv4.x, hv4.y, hv4.z, hv4.w};
            const float e0[4] = {w0.x, w0.y, w0.z, w0.w};
            const float e1[4] = {w1.x, w1.y, w1.z, w1.w};
            const float e2[4] = {w2.x, w2.y, w2.z, w2.w};
            const float e3[4] = {w3.x, w3.y, w3.z, w3.w};
#pragma unroll
            for (int e = 0; e < 4; ++e) {
                half2_t hv = __builtin_bit_cast(half2_t, he[e]);
                a0 = __builtin_amdgcn_fdot2(__builtin_bit_cast(half2_t, e0[e]), hv, a0, false);
                a1 = __builtin_amdgcn_fdot2(__builtin_bit_cast(half2_t, e1[e]), hv, a1, false);
                a2 = __builtin_amdgcn_fdot2(__builtin_bit_cast(half2_t, e2[e]), hv, a2, false);
                a3 = __builtin_amdgcn_fdot2(__builtin_bit_cast(half2_t, e3[e]), hv, a3, false);
            }
        }

        // Fold pre exactly once (lane ks owns gate ks), butterfly over 4 lanes.
        a0 += (ks == 0) ? pv : 0.f;
        a1 += (ks == 1) ? pv : 0.f;
        a2 += (ks == 2) ? pv : 0.f;
        a3 += (ks == 3) ? pv : 0.f;
#pragma unroll
        for (int d = 1; d < 4; d <<= 1) {
            a0 += __shfl_xor(a0, d);
            a1 += __shfl_xor(a1, d);
            a2 += __shfl_xor(a2, d);
            a3 += __shfl_xor(a3, d);
        }

        // All lanes: redundant gate update (bit-identical across 4 k-lanes).
        float iv = fast_sig(a0);
        float fv = fast_sig(a1);
        float gv = fast_tanh(a2);
        float ov = fast_sig(a3);
        cstate = fv * cstate + iv * gv;
        float h = ov * fast_tanh(cstate);

        unsigned hb16 = (unsigned)__builtin_bit_cast(unsigned short, (_Float16)h);
        unsigned nb = (unsigned)__shfl_xor((int)hb16, 4);   // partner jloc^1
        const int pn = par ^ 1;
        if (ks == 0) {
            ((unsigned short*)hh[pn])[jj] = (unsigned short)hb16;
        }
        if (isOut) {
            out[((size_t)seq * 384 + t) * 512 + dir * 256 + jj] = h;
        }
        if (isPub) {
            unsigned payload = (hb16 & 0xffffu) | (nb << 16);
            int P = (w << 6) + p;
            unsigned long long pk =
                ((unsigned long long)(unsigned)(s + 1) << 32) | payload;
            __hip_atomic_store(&pub[((size_t)chain * 2 + pn) * 128 + P], pk,
                               __ATOMIC_RELAXED, __HIP_MEMORY_SCOPE_AGENT);
        }
        __syncthreads();                     // hh[pn] own region complete
    }
}

// ---------------------------------------------------------------------------
// Generic NT GEMM: C[M][N] = act(scale * A[M][K] @ W[N][K]^T + bias[N])
// ---------------------------------------------------------------------------
__global__ __launch_bounds__(256) void gemm_nt_kernel(
    const float* __restrict__ A, const float* __restrict__ W,
    const float* __restrict__ bias, float* __restrict__ C,
    int M, int N, int K, float scale, int do_relu)
{
    __shared__ float As[32][68];
    __shared__ float Ws[32][68];
    const int tid = threadIdx.x;
    const int n0 = blockIdx.x * 64, m0 = blockIdx.y * 64;
    const int lr = tid >> 2;
    const int lk = (tid & 3) * 8;
    const int tm = tid >> 4, tn = tid & 15;
    float acc[4][4];
#pragma unroll
    for (int i = 0; i < 4; ++i)
#pragma unroll
        for (int j = 0; j < 4; ++j) acc[i][j] = 0.f;

    for (int kc = 0; kc < K; kc += 32) {
        float4 a0 = *(const float4*)(A + (size_t)(m0 + lr) * K + kc + lk);
        float4 a1 = *(const float4*)(A + (size_t)(m0 + lr) * K + kc + lk + 4);
        float4 w0 = *(const float4*)(W + (size_t)(n0 + lr) * K + kc + lk);
        float4 w1 = *(const float4*)(W + (size_t)(n0 + lr) * K + kc + lk + 4);
        __syncthreads();
        As[lk + 0][lr] = a0.x; As[lk + 1][lr] = a0.y; As[lk + 2][lr] = a0.z; As[lk + 3][lr] = a0.w;
        As[lk + 4][lr] = a1.x; As[lk + 5][lr] = a1.y; As[lk + 6][lr] = a1.z; As[lk + 7][lr] = a1.w;
        Ws[lk + 0][lr] = w0.x; Ws[lk + 1][lr] = w0.y; Ws[lk + 2][lr] = w0.z; Ws[lk + 3][lr] = w0.w;
        Ws[lk + 4][lr] = w1.x; Ws[lk + 5][lr] = w1.y; Ws[lk + 6][lr] = w1.z; Ws[lk + 7][lr] = w1.w;
        __syncthreads();
#pragma unroll
        for (int kk = 0; kk < 32; ++kk) {
            float4 av = *(const float4*)&As[kk][tm * 4];
            float4 wv = *(const float4*)&Ws[kk][tn * 4];
            acc[0][0] += av.x * wv.x; acc[0][1] += av.x * wv.y; acc[0][2] += av.x * wv.z; acc[0][3] += av.x * wv.w;
            acc[1][0] += av.y * wv.x; acc[1][1] += av.y * wv.y; acc[1][2] += av.y * wv.z; acc[1][3] += av.y * wv.w;
            acc[2][0] += av.z * wv.x; acc[2][1] += av.z * wv.y; acc[2][2] += av.z * wv.z; acc[2][3] += av.z * wv.w;
            acc[3][0] += av.w * wv.x; acc[3][1] += av.w * wv.y; acc[3][2] += av.w * wv.z; acc[3][3] += av.w * wv.w;
        }
    }
    float4 bv = make_float4(0.f, 0.f, 0.f, 0.f);
    if (bias) bv = *(const float4*)(bias + n0 + tn * 4);
#pragma unroll
    for (int i = 0; i < 4; ++i) {
        int m = m0 + tm * 4 + i;
        float4 v;
        v.x = scale * acc[i][0] + bv.x;
        v.y = scale * acc[i][1] + bv.y;
        v.z = scale * acc[i][2] + bv.z;
        v.w = scale * acc[i][3] + bv.w;
        if (do_relu) {
            v.x = fmaxf(v.x, 0.f); v.y = fmaxf(v.y, 0.f);
            v.z = fmaxf(v.z, 0.f); v.w = fmaxf(v.w, 0.f);
        }
        *(float4*)(C + (size_t)m * N + n0 + tn * 4) = v;
    }
}

// ---------------------------------------------------------------------------
// pairwise: out[i][j][:] = log_softmax( sum_c relu(ur'[i][c]+ul[j][c]) * woutT[c][:] + bout )
// Stride 132 + row remap -> <=2-way conflicts (R7 fix).
// ---------------------------------------------------------------------------
__global__ __launch_bounds__(256) void pairwise_kernel(
    const float* __restrict__ u,      // [768][1024]
    const float* __restrict__ woutT,  // [1024][2]
    const float* __restrict__ bout,   // [2]
    float* __restrict__ out)          // [384][384][2]
{
    __shared__ float Ur[32][132];
    __shared__ float Ul[32][132];
    __shared__ float Wo[256];
    const int tid = threadIdx.x;
    const int j0 = blockIdx.x * 32, i0 = blockIdx.y * 32;
    const int ii = tid >> 4, jj = tid & 15;
    const int il0 = ii, il1 = ii + 16;
    const int jl0 = jj, jl1 = jj + 16;
    float acc000 = 0.f, acc001 = 0.f, acc010 = 0.f, acc011 = 0.f;
    float acc100 = 0.f, acc101 = 0.f, acc110 = 0.f, acc111 = 0.f;
    const int lrw = tid >> 3;
    const int lcb = (tid & 7) * 16;

    for (int cc = 0; cc < 1024; cc += 128) {
        __syncthreads();
#pragma unroll
        for (int q = 0; q < 4; ++q) {
            *(float4*)&Ur[lrw][lcb + 4 * q] =
                *(const float4*)(u + (size_t)(i0 + lrw) * 1024 + cc + lcb + 4 * q);
            *(float4*)&Ul[lrw][lcb + 4 * q] =
                *(const float4*)(u + (size_t)(384 + j0 + lrw) * 1024 + cc + lcb + 4 * q);
        }
        if (tid < 128)
            *(float2*)&Wo[tid * 2] = *(const float2*)(woutT + (size_t)(cc + tid) * 2);
        __syncthreads();

        for (int c = 0; c < 128; c += 4) {
            float4 a0  = *(const float4*)&Ur[il0][c];
            float4 a1  = *(const float4*)&Ur[il1][c];
            float4 b0v = *(const float4*)&Ul[jl0][c];
            float4 b1v = *(const float4*)&Ul[jl1][c];
            float4 wA4 = *(const float4*)&Wo[c * 2];
            float4 wB4 = *(const float4*)&Wo[c * 2 + 4];
#define PW_STEP(AX, W0, W1)                                   \
            { float rr;                                       \
              rr = fmaxf(a0.AX + b0v.AX, 0.f); acc000 += rr*(W0); acc001 += rr*(W1); \
              rr = fmaxf(a0.AX + b1v.AX, 0.f); acc010 += rr*(W0); acc011 += rr*(W1); \
              rr = fmaxf(a1.AX + b0v.AX, 0.f); acc100 += rr*(W0); acc101 += rr*(W1); \
              rr = fmaxf(a1.AX + b1v.AX, 0.f); acc110 += rr*(W0); acc111 += rr*(W1); }
            PW_STEP(x, wA4.x, wA4.y)
            PW_STEP(y, wA4.z, wA4.w)
            PW_STEP(z, wB4.x, wB4.y)
            PW_STEP(w, wB4.z, wB4.w)
#undef PW_STEP
        }
    }
    float2 bo = *(const float2*)bout;
    float pa[2][2][2] = {{{acc000, acc001}, {acc010, acc011}},
                         {{acc100, acc101}, {acc110, acc111}}};
#pragma unroll
    for (int pi = 0; pi < 2; ++pi)
#pragma unroll
        for (int pj = 0; pj < 2; ++pj) {
            float l0 = pa[pi][pj][0] + bo.x;
            float l1 = pa[pi][pj][1] + bo.y;
            float m = fmaxf(l0, l1);
            float lse = m + logf(expf(l0 - m) + expf(l1 - m));
            int ig = i0 + ii + 16 * pi;
            int jg = j0 + jj + 16 * pj;
            float2 o2; o2.x = l0 - lse; o2.y = l1 - lse;
            *(float2*)(out + ((size_t)ig * 384 + jg) * 2) = o2;
        }
}

// ---------------------------------------------------------------------------
extern "C" void kernel_launch(void* const* d_in, const int* in_sizes, int n_in,
                              void* d_out, int out_size, void* d_ws, size_t ws_size,
                              hipStream_t stream)
{
    const float* v_r  = (const float*)d_in[0];
    const float* v_l  = (const float*)d_in[1];
    const float* Wih0 = (const float*)d_in[2];
    const float* Whh0 = (const float*)d_in[3];
    const float* bih0 = (const float*)d_in[4];
    const float* bhh0 = (const float*)d_in[5];
    const float* Wih1 = (const float*)d_in[6];
    const float* Whh1 = (const float*)d_in[7];
    const float* bih1 = (const float*)d_in[8];
    const float* bhh1 = (const float*)d_in[9];
    const float* W1   = (const float*)d_in[10];
    const float* b1   = (const float*)d_in[11];
    const float* W2   = (const float*)d_in[12];
    const float* b2   = (const float*)d_in[13];
    const float* W3   = (const float*)d_in[14];
    const float* b3   = (const float*)d_in[15];
    const float* Wout = (const float*)d_in[16];
    const float* bout = (const float*)d_in[17];
    float* out = (float*)d_out;

    float* ws = (float*)d_ws;
    size_t off = 0;
    float* b0sum = ws + off; off += 2048;
    float* b1sum = ws + off; off += 2048;
    float* W3sum = ws + off; off += 1024 * 512;
    float* woutT = ws + off; off += 2048;
    float* pre0  = ws + off; off += (size_t)4 * 384 * 1024;
    float* out0  = ws + off; off += (size_t)2 * 384 * 512;
    float* pre1  = ws + off; off += (size_t)768 * 2048;
    float* out1  = ws + off; off += (size_t)2 * 384 * 512;
    float* h1    = ws + off; off += (size_t)768 * 1024;
    float* h2    = ws + off; off += (size_t)768 * 512;
    float* u     = ws + off; off += (size_t)768 * 1024;
    unsigned long long* pub0 = (unsigned long long*)(ws + off); off += 4 * 2 * 128 * 2;
    unsigned long long* pub1 = (unsigned long long*)(ws + off); off += 4 * 2 * 128 * 2;

    prep_kernel<<<512, 256, 0, stream>>>(bih0, bhh0, bih1, bhh1, W3, Wout,
                                         b0sum, b1sum, W3sum, woutT);
    proj0_kernel<<<dim3(384, 4), 256, 0, stream>>>(v_r, v_l, Wih0, b0sum, pre0);
    lstm_rec_kernel<<<16, 512, 0, stream>>>(Whh0, pre0, out0, pub0, 0);
    gemm_nt_kernel<<<dim3(2048 / 64, 768 / 64), 256, 0, stream>>>(
        out0, Wih1, b1sum, pre1, 768, 2048, 512, 1.f, 0);
    lstm_rec_kernel<<<16, 512, 0, stream>>>(Whh1, pre1, out1, pub1, 1);
    gemm_nt_kernel<<<dim3(1024 / 64, 768 / 64), 256, 0, stream>>>(
        out1, W1, b1, h1, 768, 1024, 512, 1.f, 1);
    gemm_nt_kernel<<<dim3(512 / 64, 768 / 64), 256, 0, stream>>>(
        h1, W2, b2, h2, 768, 512, 1024, 1.f, 1);
    gemm_nt_kernel<<<dim3(1024 / 64, 384 / 64), 256, 0, stream>>>(
        h2, W3sum, b3, u, 384, 1024, 512, 0.5f, 0);
    gemm_nt_kernel<<<dim3(1024 / 64, 384 / 64), 256, 0, stream>>>(
        h2 + (size_t)384 * 512, W3sum, nullptr, u + (size_t)384 * 1024, 384, 1024, 512, 0.5f, 0);
    pairwise_kernel<<<dim3(12, 12), 256, 0, stream>>>(u, woutT, bout, out);
}

// Round 15
// 1207.374 us; speedup vs baseline: 1.5342x; 1.2504x over previous
//
#include <hip/hip_runtime.h>
#include <math.h>

// Problem constants
// H=256, D_IN=22, T=384, 4H=1024, N_R=N_L=384, H1=1024, H2=512, H3=1024, RRI=2

typedef _Float16 half2_t __attribute__((ext_vector_type(2)));

__device__ __forceinline__ float fast_sig(float x) {
    float e = __expf(-x);
    return __builtin_amdgcn_rcpf(1.f + e);
}
__device__ __forceinline__ float fast_tanh(float x) {
    x = fminf(fmaxf(x, -30.f), 30.f);
    float e = __expf(2.f * x);
    return (e - 1.f) * __builtin_amdgcn_rcpf(e + 1.f);
}

// ---------------------------------------------------------------------------
// prep
// ---------------------------------------------------------------------------
__global__ __launch_bounds__(256) void prep_kernel(
    const float* __restrict__ bih0, const float* __restrict__ bhh0,
    const float* __restrict__ bih1, const float* __restrict__ bhh1,
    const float* __restrict__ W3,   const float* __restrict__ Wout,
    float* __restrict__ b0sum, float* __restrict__ b1sum,
    float* __restrict__ W3sum, float* __restrict__ woutT)
{
    int idx = blockIdx.x * 256 + threadIdx.x;
    int stride = gridDim.x * 256;
    if (idx < 2048) {
        b0sum[idx] = bih0[idx] + bhh0[idx];
        b1sum[idx] = bih1[idx] + bhh1[idx];
        woutT[idx] = Wout[(idx & 1) * 1024 + (idx >> 1)];
    }
    for (int i = idx; i < 1024 * 512; i += stride) {
        int n = i >> 9, k = i & 511;
        W3sum[i] = W3[n * 1024 + k] + W3[n * 1024 + 512 + k];
    }
}

// ---------------------------------------------------------------------------
// proj0
// ---------------------------------------------------------------------------
__global__ __launch_bounds__(256) void proj0_kernel(
    const float* __restrict__ v_r, const float* __restrict__ v_l,
    const float* __restrict__ Wih0, const float* __restrict__ b0sum,
    float* __restrict__ pre0)
{
    int t = blockIdx.x;
    int sd = blockIdx.y;            // seq*2 + dir
    int seq = sd >> 1, dir = sd & 1;
    const float* x = (seq ? v_l : v_r) + t * 22;
    __shared__ float sx[22];
    if (threadIdx.x < 22) sx[threadIdx.x] = x[threadIdx.x];
    __syncthreads();
#pragma unroll
    for (int q = 0; q < 4; ++q) {
        int o = q * 256 + threadIdx.x;
        const float* wr = Wih0 + (size_t)(dir * 1024 + o) * 22;
        float acc = b0sum[dir * 1024 + o];
#pragma unroll
        for (int d = 0; d < 22; ++d) acc += sx[d] * wr[d];
        pre0[((size_t)sd * 384 + t) * 1024 + o] = acc;
    }
}

// ---------------------------------------------------------------------------
// LSTM recurrence, v15: 4 WGs/chain, ALL weights register-resident — zero
// weight streaming.
// R10/R11/R14 model: step = ~1600-2000 cyc protocol + weight-restream
// (~1500-2900 cyc for 128 KB/step from scratch-spill OR LDS). Only a 4-WG
// split puts the whole 512 KB f16 chain weight set in registers at 64
// pinned floats/thread (fits the ~128-VGPR tier verified in R11-R14 —
// the allocator spills anything bigger, ignoring all occupancy hints).
// Grid 32, block 512: chain=b&7 (>=4 exit), w=b>>3 in [0,4); chain's 4 WGs
// co-located on XCD chain (%8 round-robin). 16 active CUs.
// Thread (jloc=t>>3, ks=t&7): owns 4 gate rows {g*256+jj}, jj=w*64+jloc,
// k in [32ks,32ks+32) -> 4x16 half2 = 64 pinned floats.
// Step s (v10 protocol, 4 parties):
//   [ks in {6,7}, cid<96: poll 3 peers' tag-s pair packets -> hh[par] remote]
//   [barrier]  (hh[par] = full h_{s-1})
//   [all: 4x ds_read_b128 (segment stride 5 float4 -> bank bases
//    {0,20,8,28,16,4,24,12}, conflict-free) + 64 fdot2 -> fold pre (lane
//    ks<4 owns gate ks) -> butterfly d=1,2,4 -> ALL lanes hold 4 gate sums
//    -> redundant bit-identical c/h (R8)]
//   [ks==0: hh[pn] f16 write + (jloc even) publish pair tag s+1;
//    ks==1: out store]
//   [barrier]
// Poll(tag s) precedes publish(tag s+1) in wave program order — safe: tag-s
// publishes happened in the PREVIOUS iteration (v10-proven; the R3/R4
// hazard needed poll blocking same-tag publish). Slot reuse safe for 4
// parties: A's overwrite of parity slot (tag s+2, its phase 4 of s+1)
// happens after A's phase-1 poll of tag s+1 from ALL peers, which follows
// each peer's phase-4 publish of s+1, which follows that peer's phase-1
// consume of tag s. Bounded s_sleep spin (R4).
// ---------------------------------------------------------------------------
__global__ __launch_bounds__(512) void lstm_rec_kernel(
    const float* __restrict__ Whh,   // [2][1024][256] fp32
    const float* __restrict__ pre,   // layer0: [(seq*2+dir)][384][1024]; layer1: [(seq*384+t)][2][1024]
    float* __restrict__ out,         // [2][384][512]  (cols: dir*256 + j)
    unsigned long long* pub,         // [4 chains][2 parity][128]
    int layer)
{
    const int b = blockIdx.x;
    const int chain = b & 7;                 // XCD id under %8 round-robin
    const int w = b >> 3;                    // 0..3
    if (chain >= 4) return;
    const int seq = chain >> 1, dir = chain & 1;
    const int tid = threadIdx.x;
    const int ks = tid & 7;                  // 32-wide k-slice
    const int jloc = tid >> 3;               // 0..63
    const int jj = (w << 6) + jloc;          // own h index

    // h in LDS: 8 segments (one per k-slice) of 16 half2, stride 5 float4
    // (4 used + 1 pad) -> the 8 broadcast b128 reads tile all 32 banks.
    __shared__ __align__(16) float4 hh4[2][40];

    // 64 pinned register weights: wA[g*16+q] = half2 (k=32ks+2q) of row g*256+jj.
    float wA[64];
#pragma unroll
    for (int g = 0; g < 4; ++g) {
        const float* wr = Whh + (((size_t)(dir * 1024 + g * 256 + jj)) << 8) + (ks << 5);
#pragma unroll
        for (int q = 0; q < 16; ++q) {
            float2 v = *(const float2*)(wr + 2 * q);
            half2_t h2; h2.x = (_Float16)v.x; h2.y = (_Float16)v.y;
            wA[g * 16 + q] = __builtin_bit_cast(float, h2);
        }
    }
#pragma unroll
    for (int q = 0; q < 64; ++q) asm volatile("" : "+v"(wA[q]));

    if (tid < 320) ((float*)hh4)[tid] = 0.f;    // both parities zeroed
    float cstate = 0.f;                      // redundant in 8 lanes, bit-identical
    __syncthreads();

    for (int s = 0; s < 384; ++s) {
        const int t = dir ? (383 - s) : s;
        const float* pre_t = (layer == 0)
            ? pre + ((size_t)(seq * 2 + dir) * 384 + t) * 1024
            : pre + (((size_t)(seq * 384 + t)) * 2 + dir) * 1024;
        float pv = (ks < 4) ? pre_t[(ks << 8) + jj] : 0.f;  // drains under fdot

        const int par = s & 1, pn = par ^ 1;
        // ---- Phase 1: poll 3 peers' h_{s-1} (tag s) ----
        if (s > 0 && ks >= 6) {
            int cid = (jloc << 1) | (ks - 6);       // 0..127
            if (cid < 96) {
                int peer = cid >> 5;                // 0..2
                int p = cid & 31;
                int wp = (w + 1 + peer) & 3;
                int P = (wp << 5) + p;              // global pair index
                const unsigned long long* src =
                    &pub[((size_t)chain * 2 + par) * 128 + P];
                const unsigned expect = (unsigned)s;
                unsigned long long v =
                    __hip_atomic_load(src, __ATOMIC_RELAXED, __HIP_MEMORY_SCOPE_AGENT);
                if ((unsigned)(v >> 32) != expect) {
                    for (int it = 0; it < 65536; ++it) {
                        __builtin_amdgcn_s_sleep(1);
                        v = __hip_atomic_load(src, __ATOMIC_RELAXED, __HIP_MEMORY_SCOPE_AGENT);
                        if ((unsigned)(v >> 32) == expect) break;
                    }
                }
                ((half2_t*)&hh4[par][0])[(P >> 4) * 20 + (P & 15)] =
                    __builtin_bit_cast(half2_t, (unsigned)v);
            }
        }
        __syncthreads();                     // hh4[par] = complete h_{s-1}

        // ---- Phase 2: fdot over own k-slice, all weights in registers ----
        const float4* hb = &hh4[par][ks * 5];
        float4 hl0 = hb[0], hl1 = hb[1], hl2 = hb[2], hl3 = hb[3];
        const float4 hls[4] = {hl0, hl1, hl2, hl3};
        float a0 = 0.f, a1 = 0.f, a2 = 0.f, a3 = 0.f;
#pragma unroll
        for (int m = 0; m < 4; ++m) {
            const float he[4] = {hls[m].x, hls[m].y, hls[m].z, hls[m].w};
#pragma unroll
            for (int e = 0; e < 4; ++e) {
                half2_t hv = __builtin_bit_cast(half2_t, he[e]);
                int q = 4 * m + e;
                a0 = __builtin_amdgcn_fdot2(__builtin_bit_cast(half2_t, wA[q]),      hv, a0, false);
                a1 = __builtin_amdgcn_fdot2(__builtin_bit_cast(half2_t, wA[16 + q]), hv, a1, false);
                a2 = __builtin_amdgcn_fdot2(__builtin_bit_cast(half2_t, wA[32 + q]), hv, a2, false);
                a3 = __builtin_amdgcn_fdot2(__builtin_bit_cast(half2_t, wA[48 + q]), hv, a3, false);
            }
        }
        // Fold pre exactly once (lane ks<4 owns gate ks), butterfly 8 lanes.
        a0 += (ks == 0) ? pv : 0.f;
        a1 += (ks == 1) ? pv : 0.f;
        a2 += (ks == 2) ? pv : 0.f;
        a3 += (ks == 3) ? pv : 0.f;
#pragma unroll
        for (int d = 1; d < 8; d <<= 1) {
            a0 += __shfl_xor(a0, d);
            a1 += __shfl_xor(a1, d);
            a2 += __shfl_xor(a2, d);
            a3 += __shfl_xor(a3, d);
        }

        // All lanes: redundant gate update (bit-identical across 8 k-lanes).
        float iv = fast_sig(a0);
        float fv = fast_sig(a1);
        float gv = fast_tanh(a2);
        float ov = fast_sig(a3);
        cstate = fv * cstate + iv * gv;
        float h = ov * fast_tanh(cstate);

        unsigned hb16 = (unsigned)__builtin_bit_cast(unsigned short, (_Float16)h);
        unsigned nb = (unsigned)__shfl_xor((int)hb16, 8);   // partner jloc^1
        if (ks == 0) {
            ((unsigned short*)&hh4[pn][0])[(jj >> 5) * 40 + (jj & 31)] =
                (unsigned short)hb16;
            if ((jloc & 1) == 0) {
                unsigned payload = (hb16 & 0xffffu) | (nb << 16);
                int P = (w << 5) + (jloc >> 1);
                unsigned long long pk =
                    ((unsigned long long)(unsigned)(s + 1) << 32) | payload;
                __hip_atomic_store(&pub[((size_t)chain * 2 + pn) * 128 + P], pk,
                                   __ATOMIC_RELAXED, __HIP_MEMORY_SCOPE_AGENT);
            }
        }
        if (ks == 1) {
            out[((size_t)seq * 384 + t) * 512 + dir * 256 + jj] = h;
        }
        __syncthreads();                     // hh4[pn] own region complete
    }
}

// ---------------------------------------------------------------------------
// Generic NT GEMM: C[M][N] = act(scale * A[M][K] @ W[N][K]^T + bias[N])
// ---------------------------------------------------------------------------
__global__ __launch_bounds__(256) void gemm_nt_kernel(
    const float* __restrict__ A, const float* __restrict__ W,
    const float* __restrict__ bias, float* __restrict__ C,
    int M, int N, int K, float scale, int do_relu)
{
    __shared__ float As[32][68];
    __shared__ float Ws[32][68];
    const int tid = threadIdx.x;
    const int n0 = blockIdx.x * 64, m0 = blockIdx.y * 64;
    const int lr = tid >> 2;
    const int lk = (tid & 3) * 8;
    const int tm = tid >> 4, tn = tid & 15;
    float acc[4][4];
#pragma unroll
    for (int i = 0; i < 4; ++i)
#pragma unroll
        for (int j = 0; j < 4; ++j) acc[i][j] = 0.f;

    for (int kc = 0; kc < K; kc += 32) {
        float4 a0 = *(const float4*)(A + (size_t)(m0 + lr) * K + kc + lk);
        float4 a1 = *(const float4*)(A + (size_t)(m0 + lr) * K + kc + lk + 4);
        float4 w0 = *(const float4*)(W + (size_t)(n0 + lr) * K + kc + lk);
        float4 w1 = *(const float4*)(W + (size_t)(n0 + lr) * K + kc + lk + 4);
        __syncthreads();
        As[lk + 0][lr] = a0.x; As[lk + 1][lr] = a0.y; As[lk + 2][lr] = a0.z; As[lk + 3][lr] = a0.w;
        As[lk + 4][lr] = a1.x; As[lk + 5][lr] = a1.y; As[lk + 6][lr] = a1.z; As[lk + 7][lr] = a1.w;
        Ws[lk + 0][lr] = w0.x; Ws[lk + 1][lr] = w0.y; Ws[lk + 2][lr] = w0.z; Ws[lk + 3][lr] = w0.w;
        Ws[lk + 4][lr] = w1.x; Ws[lk + 5][lr] = w1.y; Ws[lk + 6][lr] = w1.z; Ws[lk + 7][lr] = w1.w;
        __syncthreads();
#pragma unroll
        for (int kk = 0; kk < 32; ++kk) {
            float4 av = *(const float4*)&As[kk][tm * 4];
            float4 wv = *(const float4*)&Ws[kk][tn * 4];
            acc[0][0] += av.x * wv.x; acc[0][1] += av.x * wv.y; acc[0][2] += av.x * wv.z; acc[0][3] += av.x * wv.w;
            acc[1][0] += av.y * wv.x; acc[1][1] += av.y * wv.y; acc[1][2] += av.y * wv.z; acc[1][3] += av.y * wv.w;
            acc[2][0] += av.z * wv.x; acc[2][1] += av.z * wv.y; acc[2][2] += av.z * wv.z; acc[2][3] += av.z * wv.w;
            acc[3][0] += av.w * wv.x; acc[3][1] += av.w * wv.y; acc[3][2] += av.w * wv.z; acc[3][3] += av.w * wv.w;
        }
    }
    float4 bv = make_float4(0.f, 0.f, 0.f, 0.f);
    if (bias) bv = *(const float4*)(bias + n0 + tn * 4);
#pragma unroll
    for (int i = 0; i < 4; ++i) {
        int m = m0 + tm * 4 + i;
        float4 v;
        v.x = scale * acc[i][0] + bv.x;
        v.y = scale * acc[i][1] + bv.y;
        v.z = scale * acc[i][2] + bv.z;
        v.w = scale * acc[i][3] + bv.w;
        if (do_relu) {
            v.x = fmaxf(v.x, 0.f); v.y = fmaxf(v.y, 0.f);
            v.z = fmaxf(v.z, 0.f); v.w = fmaxf(v.w, 0.f);
        }
        *(float4*)(C + (size_t)m * N + n0 + tn * 4) = v;
    }
}

// ---------------------------------------------------------------------------
// pairwise: out[i][j][:] = log_softmax( sum_c relu(ur'[i][c]+ul[j][c]) * woutT[c][:] + bout )
// Stride 132 + row remap -> <=2-way conflicts (R7 fix).
// ---------------------------------------------------------------------------
__global__ __launch_bounds__(256) void pairwise_kernel(
    const float* __restrict__ u,      // [768][1024]
    const float* __restrict__ woutT,  // [1024][2]
    const float* __restrict__ bout,   // [2]
    float* __restrict__ out)          // [384][384][2]
{
    __shared__ float Ur[32][132];
    __shared__ float Ul[32][132];
    __shared__ float Wo[256];
    const int tid = threadIdx.x;
    const int j0 = blockIdx.x * 32, i0 = blockIdx.y * 32;
    const int ii = tid >> 4, jj = tid & 15;
    const int il0 = ii, il1 = ii + 16;
    const int jl0 = jj, jl1 = jj + 16;
    float acc000 = 0.f, acc001 = 0.f, acc010 = 0.f, acc011 = 0.f;
    float acc100 = 0.f, acc101 = 0.f, acc110 = 0.f, acc111 = 0.f;
    const int lrw = tid >> 3;
    const int lcb = (tid & 7) * 16;

    for (int cc = 0; cc < 1024; cc += 128) {
        __syncthreads();
#pragma unroll
        for (int q = 0; q < 4; ++q) {
            *(float4*)&Ur[lrw][lcb + 4 * q] =
                *(const float4*)(u + (size_t)(i0 + lrw) * 1024 + cc + lcb + 4 * q);
            *(float4*)&Ul[lrw][lcb + 4 * q] =
                *(const float4*)(u + (size_t)(384 + j0 + lrw) * 1024 + cc + lcb + 4 * q);
        }
        if (tid < 128)
            *(float2*)&Wo[tid * 2] = *(const float2*)(woutT + (size_t)(cc + tid) * 2);
        __syncthreads();

        for (int c = 0; c < 128; c += 4) {
            float4 a0  = *(const float4*)&Ur[il0][c];
            float4 a1  = *(const float4*)&Ur[il1][c];
            float4 b0v = *(const float4*)&Ul[jl0][c];
            float4 b1v = *(const float4*)&Ul[jl1][c];
            float4 wA4 = *(const float4*)&Wo[c * 2];
            float4 wB4 = *(const float4*)&Wo[c * 2 + 4];
#define PW_STEP(AX, W0, W1)                                   \
            { float rr;                                       \
              rr = fmaxf(a0.AX + b0v.AX, 0.f); acc000 += rr*(W0); acc001 += rr*(W1); \
              rr = fmaxf(a0.AX + b1v.AX, 0.f); acc010 += rr*(W0); acc011 += rr*(W1); \
              rr = fmaxf(a1.AX + b0v.AX, 0.f); acc100 += rr*(W0); acc101 += rr*(W1); \
              rr = fmaxf(a1.AX + b1v.AX, 0.f); acc110 += rr*(W0); acc111 += rr*(W1); }
            PW_STEP(x, wA4.x, wA4.y)
            PW_STEP(y, wA4.z, wA4.w)
            PW_STEP(z, wB4.x, wB4.y)
            PW_STEP(w, wB4.z, wB4.w)
#undef PW_STEP
        }
    }
    float2 bo = *(const float2*)bout;
    float pa[2][2][2] = {{{acc000, acc001}, {acc010, acc011}},
                         {{acc100, acc101}, {acc110, acc111}}};
#pragma unroll
    for (int pi = 0; pi < 2; ++pi)
#pragma unroll
        for (int pj = 0; pj < 2; ++pj) {
            float l0 = pa[pi][pj][0] + bo.x;
            float l1 = pa[pi][pj][1] + bo.y;
            float m = fmaxf(l0, l1);
            float lse = m + logf(expf(l0 - m) + expf(l1 - m));
            int ig = i0 + ii + 16 * pi;
            int jg = j0 + jj + 16 * pj;
            float2 o2; o2.x = l0 - lse; o2.y = l1 - lse;
            *(float2*)(out + ((size_t)ig * 384 + jg) * 2) = o2;
        }
}

// ---------------------------------------------------------------------------
extern "C" void kernel_launch(void* const* d_in, const int* in_sizes, int n_in,
                              void* d_out, int out_size, void* d_ws, size_t ws_size,
                              hipStream_t stream)
{
    const float* v_r  = (const float*)d_in[0];
    const float* v_l  = (const float*)d_in[1];
    const float* Wih0 = (const float*)d_in[2];
    const float* Whh0 = (const float*)d_in[3];
    const float* bih0 = (const float*)d_in[4];
    const float* bhh0 = (const float*)d_in[5];
    const float* Wih1 = (const float*)d_in[6];
    const float* Whh1 = (const float*)d_in[7];
    const float* bih1 = (const float*)d_in[8];
    const float* bhh1 = (const float*)d_in[9];
    const float* W1   = (const float*)d_in[10];
    const float* b1   = (const float*)d_in[11];
    const float* W2   = (const float*)d_in[12];
    const float* b2   = (const float*)d_in[13];
    const float* W3   = (const float*)d_in[14];
    const float* b3   = (const float*)d_in[15];
    const float* Wout = (const float*)d_in[16];
    const float* bout = (const float*)d_in[17];
    float* out = (float*)d_out;

    float* ws = (float*)d_ws;
    size_t off = 0;
    float* b0sum = ws + off; off += 2048;
    float* b1sum = ws + off; off += 2048;
    float* W3sum = ws + off; off += 1024 * 512;
    float* woutT = ws + off; off += 2048;
    float* pre0  = ws + off; off += (size_t)4 * 384 * 1024;
    float* out0  = ws + off; off += (size_t)2 * 384 * 512;
    float* pre1  = ws + off; off += (size_t)768 * 2048;
    float* out1  = ws + off; off += (size_t)2 * 384 * 512;
    float* h1    = ws + off; off += (size_t)768 * 1024;
    float* h2    = ws + off; off += (size_t)768 * 512;
    float* u     = ws + off; off += (size_t)768 * 1024;
    unsigned long long* pub0 = (unsigned long long*)(ws + off); off += 4 * 2 * 128 * 2;
    unsigned long long* pub1 = (unsigned long long*)(ws + off); off += 4 * 2 * 128 * 2;

    prep_kernel<<<512, 256, 0, stream>>>(bih0, bhh0, bih1, bhh1, W3, Wout,
                                         b0sum, b1sum, W3sum, woutT);
    proj0_kernel<<<dim3(384, 4), 256, 0, stream>>>(v_r, v_l, Wih0, b0sum, pre0);
    lstm_rec_kernel<<<32, 512, 0, stream>>>(Whh0, pre0, out0, pub0, 0);
    gemm_nt_kernel<<<dim3(2048 / 64, 768 / 64), 256, 0, stream>>>(
        out0, Wih1, b1sum, pre1, 768, 2048, 512, 1.f, 0);
    lstm_rec_kernel<<<32, 512, 0, stream>>>(Whh1, pre1, out1, pub1, 1);
    gemm_nt_kernel<<<dim3(1024 / 64, 768 / 64), 256, 0, stream>>>(
        out1, W1, b1, h1, 768, 1024, 512, 1.f, 1);
    gemm_nt_kernel<<<dim3(512 / 64, 768 / 64), 256, 0, stream>>>(
        h1, W2, b2, h2, 768, 512, 1024, 1.f, 1);
    gemm_nt_kernel<<<dim3(1024 / 64, 384 / 64), 256, 0, stream>>>(
        h2, W3sum, b3, u, 384, 1024, 512, 0.5f, 0);
    gemm_nt_kernel<<<dim3(1024 / 64, 384 / 64), 256, 0, stream>>>(
        h2 + (size_t)384 * 512, W3sum, nullptr, u + (size_t)384 * 1024, 384, 1024, 512, 0.5f, 0);
    pairwise_kernel<<<dim3(12, 12), 256, 0, stream>>>(u, woutT, bout, out);
}